// Round 2
// baseline (210.498 us; speedup 1.0000x reference)
//
#include <hip/hip_runtime.h>
#include <math.h>

// Single-column ocean model: 2048 cols x 128 levels, 400 steps, 10 snapshots.
// One wave = 2 columns x 2 fields; each column-field = one 16-lane DPP row,
// 8 vertical levels per lane. Tridiag solves via affine scans with
// precomputed (time-invariant) stage multipliers; all state in registers.

namespace {
constexpr int NZv   = 128;
constexpr int Bv    = 2048;
constexpr int NTv   = 400;
constexpr int NOUTv = 40;
constexpr int NSNAP = NTv / NOUTv; // 10
constexpr float DTf      = 50.0f;
constexpr float FCORf    = 1.0e-4f;
constexpr float TFLX_SFC = -5.0e-5f;
constexpr float SFLX_SFC = 1.0e-6f;
constexpr float RFLX_SFC = 3.7e-5f;
constexpr float USTR_SFC = 1.0e-4f;
constexpr float CPf      = 3985.0f;

template <int CTRL>
__device__ __forceinline__ float dpp_zero(float x) {
  // shift with 0-fill at row boundary (bound_ctrl = true)
  return __int_as_float(__builtin_amdgcn_update_dpp(
      0, __float_as_int(x), CTRL, 0xF, 0xF, true));
}
template <int CTRL>
__device__ __forceinline__ float dpp_one(float x) {
  // shift with 1.0-fill at row boundary (old = 1.0f, bound_ctrl = false)
  return __int_as_float(__builtin_amdgcn_update_dpp(
      0x3f800000, __float_as_int(x), CTRL, 0xF, 0xF, false));
}
} // namespace

__global__ __launch_bounds__(256, 2) void scm_kernel(
    const float* __restrict__ u_in, const float* __restrict__ v_in,
    const float* __restrict__ t_in, const float* __restrict__ s_in,
    const float* __restrict__ akv,  const float* __restrict__ akt,
    const float* __restrict__ eps,  const float* __restrict__ hz,
    float* __restrict__ out) {
  __shared__ float zw[NZv + 1];
  __shared__ float sh_abc[4][2][3][NZv]; // [wave][col][a,b,c][k]
  __shared__ float sh_cpp[4][2][2][NZv]; // [wave][col][cp,p][k]

  const int tid     = threadIdx.x;
  const int lane    = tid & 63;
  const int wid     = tid >> 6;           // 0..3
  const bool isM    = (wid & 1) != 0;     // momentum wave (u,v) vs tracer (t,s)
  const int half    = lane >> 5;          // field within wave: 0=t|u, 1=s|v
  const int seg     = (lane >> 4) & 1;    // column within pair
  const int segLane = lane & 15;          // 16-lane DPP row position
  const int cpair   = blockIdx.x * 2 + (wid >> 1);
  const int col     = cpair * 2 + seg;
  const int k0      = segLane * 8;

  // ---- zw (w-point depths, cumsum of hz) -------------------------------
  if (tid == 0) {
    float tot = 0.f;
    for (int k = 0; k < NZv; ++k) tot += hz[k];
    float run = 0.f;
    zw[0] = -tot;
    for (int k = 0; k < NZv; ++k) { run += hz[k]; zw[k + 1] = run - tot; }
  }
  __syncthreads();

  // ---- tridiag coefficients (fixed in time) ----------------------------
  const float* Kp = isM ? akv : akt;
  float a_[8], c_[8], b_[8], hzv[8];
#pragma unroll
  for (int j = 0; j < 8; ++j) {
    const int k = k0 + j;
    const float hzk = hz[k];
    hzv[j] = hzk;
    const float Kk  = Kp[col * (NZv + 1) + k];
    const float Kk1 = Kp[col * (NZv + 1) + k + 1];
    float aj = 0.f, cj = 0.f;
    if (k > 0)        { const float dzm = 0.5f * (hz[k - 1] + hzk); aj = -DTf * Kk  / (hzk * dzm); }
    if (k < NZv - 1)  { const float dzp = 0.5f * (hzk + hz[k + 1]); cj = -DTf * Kk1 / (hzk * dzp); }
    a_[j] = aj; c_[j] = cj; b_[j] = 1.f - aj - cj;
  }
  if (half == 0) {
#pragma unroll
    for (int j = 0; j < 8; ++j) {
      sh_abc[wid][seg][0][k0 + j] = a_[j];
      sh_abc[wid][seg][1][k0 + j] = b_[j];
      sh_abc[wid][seg][2][k0 + j] = c_[j];
    }
  }
  __syncthreads();
  // serial Thomas factorization per column (one-time)
  if (half == 0 && segLane == 0) {
    float cpp = 0.f;
    for (int k = 0; k < NZv; ++k) {
      const float aa = sh_abc[wid][seg][0][k];
      const float bb = sh_abc[wid][seg][1][k];
      const float cc = sh_abc[wid][seg][2][k];
      const float den = bb - aa * cpp;
      const float pp  = 1.f / den;
      const float cpk = cc * pp;
      sh_cpp[wid][seg][0][k] = cpk;
      sh_cpp[wid][seg][1][k] = pp;
      cpp = cpk;
    }
  }
  __syncthreads();

  float p_[8], Ab[8], A_[8];
#pragma unroll
  for (int j = 0; j < 8; ++j) {
    Ab[j] = -sh_cpp[wid][seg][0][k0 + j];  // backward multiplier = -cp_k
    p_[j] =  sh_cpp[wid][seg][1][k0 + j];  // 1/den
    A_[j] = -a_[j] * p_[j];                // forward multiplier
  }
  float Ap[7];                              // forward local prefix products
  Ap[0] = A_[0];
#pragma unroll
  for (int j = 1; j < 7; ++j) Ap[j] = A_[j] * Ap[j - 1];
  const float Afull = A_[7] * Ap[6];

  float Absuf[8];                           // backward local suffix products
  Absuf[7] = Ab[7];
#pragma unroll
  for (int j = 6; j >= 0; --j) Absuf[j] = Ab[j] * Absuf[j + 1];
  const float Abfull = Absuf[0];

  // stage multipliers for the lane scans (fixed in time)
  float As[4], Bs[4];
  {
    float Ar = Afull;
    As[0] = Ar; Ar *= dpp_one<0x111>(Ar);   // row_shr:1
    As[1] = Ar; Ar *= dpp_one<0x112>(Ar);   // row_shr:2
    As[2] = Ar; Ar *= dpp_one<0x114>(Ar);   // row_shr:4
    As[3] = Ar; Ar *= dpp_one<0x118>(Ar);   // row_shr:8
    float Br = Abfull;
    Bs[0] = Br; Br *= dpp_one<0x101>(Br);   // row_shl:1
    Bs[1] = Br; Br *= dpp_one<0x102>(Br);   // row_shl:2
    Bs[2] = Br; Br *= dpp_one<0x104>(Br);   // row_shl:4
    Bs[3] = Br; Br *= dpp_one<0x108>(Br);   // row_shl:8
  }

  // ---- forcing (fixed in time) -----------------------------------------
  float frc[8];
  const float hz_top = hz[NZv - 1];
  if (!isM) {
    if (half == 0) {  // temperature: penetrative solar + sfc flux + dissipation
#pragma unroll
      for (int j = 0; j < 8; ++j) {
        const int k = k0 + j;
        const float zk = zw[k], zk1 = zw[k + 1];
        const float fck  = RFLX_SFC * (0.58f * expf(zk  * (1.f / 0.35f)) + 0.42f * expf(zk  * (1.f / 23.f)));
        const float fck1 = RFLX_SFC * (0.58f * expf(zk1 * (1.f / 0.35f)) + 0.42f * expf(zk1 * (1.f / 23.f)));
        float div = (fck1 - fck) / hzv[j];
        if (k == NZv - 1) div += TFLX_SFC / hz_top;
        const float ec = 0.5f * (eps[col * (NZv + 1) + k] + eps[col * (NZv + 1) + k + 1]);
        frc[j] = DTf * (div + ec * (1.f / CPf));
      }
    } else {          // salinity: surface flux only
#pragma unroll
      for (int j = 0; j < 8; ++j)
        frc[j] = (k0 + j == NZv - 1) ? DTf * SFLX_SFC / hz_top : 0.f;
    }
  } else {            // momentum: wind stress on u at surface (VSTR=0, BTM=0)
#pragma unroll
    for (int j = 0; j < 8; ++j) frc[j] = 0.f;
    if (half == 0 && segLane == 15) frc[7] = DTf * USTR_SFC / hz_top;
  }

  const float g    = DTf * FCORf;
  const float cinv = 1.f / (1.f + g * g);
  const float sgng = (half == 0) ? g : -g;

  // ---- state load -------------------------------------------------------
  const float* fp = isM ? (half ? v_in : u_in) : (half ? s_in : t_in);
  float st[8];
  {
    const float4 lo = *(const float4*)(fp + (size_t)col * NZv + k0);
    const float4 hi = *(const float4*)(fp + (size_t)col * NZv + k0 + 4);
    st[0] = lo.x; st[1] = lo.y; st[2] = lo.z; st[3] = lo.w;
    st[4] = hi.x; st[5] = hi.y; st[6] = hi.z; st[7] = hi.w;
  }
  const int fidx = isM ? half : 2 + half;   // output field order: u,v,t,s
  float* outb = out + ((size_t)fidx * NSNAP * Bv + col) * NZv + k0;

  // ---- time loop --------------------------------------------------------
#pragma unroll 1
  for (int ch = 0; ch < NSNAP; ++ch) {
    float* ob = outb + (size_t)ch * Bv * NZv;
    *(float4*)(ob)     = make_float4(st[0], st[1], st[2], st[3]);
    *(float4*)(ob + 4) = make_float4(st[4], st[5], st[6], st[7]);
#pragma unroll 1
    for (int it = 0; it < NOUTv; ++it) {
      float d_[8];
      if (isM) {
        // semi-implicit Coriolis: u1=(u+g v)inv, v1=(v-g u)inv  (+ stress)
#pragma unroll
        for (int j = 0; j < 8; ++j) {
          const float oth = __shfl_xor(st[j], 32);
          d_[j] = fmaf(sgng, oth, st[j]) * cinv + frc[j];
        }
      } else {
#pragma unroll
        for (int j = 0; j < 8; ++j) d_[j] = st[j] + frc[j];
      }
      // forward sweep: dp_k = p_k d_k + A_k dp_{k-1}
      float P[8];
      P[0] = p_[0] * d_[0];
#pragma unroll
      for (int j = 1; j < 8; ++j) P[j] = fmaf(A_[j], P[j - 1], p_[j] * d_[j]);
      float S = P[7];
      S = fmaf(As[0], dpp_zero<0x111>(S), S);
      S = fmaf(As[1], dpp_zero<0x112>(S), S);
      S = fmaf(As[2], dpp_zero<0x114>(S), S);
      S = fmaf(As[3], dpp_zero<0x118>(S), S);
      const float X = dpp_zero<0x111>(S);   // dp at previous lane's last elem
      float dp[8];
      dp[7] = S;
#pragma unroll
      for (int j = 0; j < 7; ++j) dp[j] = fmaf(Ap[j], X, P[j]);
      // backward sweep: x_k = dp_k + Ab_k x_{k+1}
      float Sp[8];
      Sp[7] = dp[7];
#pragma unroll
      for (int j = 6; j >= 0; --j) Sp[j] = fmaf(Ab[j], Sp[j + 1], dp[j]);
      float T = Sp[0];
      T = fmaf(Bs[0], dpp_zero<0x101>(T), T);
      T = fmaf(Bs[1], dpp_zero<0x102>(T), T);
      T = fmaf(Bs[2], dpp_zero<0x104>(T), T);
      T = fmaf(Bs[3], dpp_zero<0x108>(T), T);
      const float Xb = dpp_zero<0x101>(T);  // x at next lane's first elem
      st[0] = T;
#pragma unroll
      for (int j = 1; j < 8; ++j) st[j] = fmaf(Absuf[j], Xb, Sp[j]);
    }
  }
}

extern "C" void kernel_launch(void* const* d_in, const int* in_sizes, int n_in,
                              void* d_out, int out_size, void* d_ws, size_t ws_size,
                              hipStream_t stream) {
  const float* u   = (const float*)d_in[0];
  const float* v   = (const float*)d_in[1];
  const float* t   = (const float*)d_in[2];
  const float* s   = (const float*)d_in[3];
  const float* akv = (const float*)d_in[4];
  const float* akt = (const float*)d_in[5];
  const float* eps = (const float*)d_in[6];
  const float* hz  = (const float*)d_in[7];
  (void)in_sizes; (void)n_in; (void)d_ws; (void)ws_size; (void)out_size;
  // 512 blocks x 256 threads: block handles 4 columns (2 pairs x {TS, M} waves)
  scm_kernel<<<dim3(Bv / 4), dim3(256), 0, stream>>>(
      u, v, t, s, akv, akt, eps, hz, (float*)d_out);
}